// Round 10
// baseline (57.960 us; speedup 1.0000x reference)
//
#include <hip/hip_runtime.h>

// B=64, IDF=128, CDF=256, L=256, S2=1024.
// Two kernels:
//   k_tcvt_all : W -> W^T fp16 + W fp16 ; ctx -> ctx^T fp16 + ctx fp16
//   k_mega     : per (batch, 32-row band): 40-chunk global_load_lds stream
//     chunks  0-15: M = wc @ W^T   (A: wc f32->fp16 via smC, acc -> smA)
//     chunks 16-19: logits = M @ ctx^T  -> softmax -> P (smA), out2 = P^T
//     chunks 20-23: Yt = P @ ctx^T'     (acc -> smA)
//     chunks 24-39: out1 = Yt @ W^T'    (aY regs x Wp chunks)

typedef unsigned short u16;
typedef _Float16 f16;
typedef __attribute__((ext_vector_type(8))) _Float16 f16x8;    // 4 VGPRs
typedef __attribute__((ext_vector_type(4))) float f32x4;       // MFMA acc
typedef __attribute__((ext_vector_type(4))) unsigned int u32x4;

#define MFMA_F16(a, b, c) __builtin_amdgcn_mfma_f32_16x16x32_f16((a), (b), (c), 0, 0, 0)

__device__ __forceinline__ u16 f2h(float v) {
    f16 h = (f16)v;                      // v_cvt_f16_f32, RNE
    return __builtin_bit_cast(u16, h);
}
__device__ __forceinline__ float h2f(u16 h) {
    return (float)__builtin_bit_cast(f16, h);
}
__device__ __forceinline__ unsigned pk2h(float a, float b) {
    return (unsigned)f2h(a) | ((unsigned)f2h(b) << 16);
}
__device__ __forceinline__ int xcd_swz(int bid, int nwg) {
    return (bid & 7) * (nwg >> 3) + (bid >> 3);
}
// async global->LDS, 16 B per lane; LDS dest is wave-uniform base + lane*16
__device__ __forceinline__ void gload16(const u16* g, u16* l) {
    __builtin_amdgcn_global_load_lds(
        (__attribute__((address_space(1))) void*)(u16*)g,
        (__attribute__((address_space(3))) void*)l, 16, 0, 0);
}

// ---------------------------------------------------------------------------
// Converts: z<64 -> ctx mat z: CtP (plain fp16) + CtH (transposed fp16);
//           z>=64 -> W band: Wp (plain fp16) + WtH (transposed fp16).
__global__ void k_tcvt_all(const float* __restrict__ Wsrc,
                           const float* __restrict__ ctx,
                           u16* __restrict__ WtH, u16* __restrict__ Wp,
                           u16* __restrict__ CtH, u16* __restrict__ CtP) {
    __shared__ float tile[32][33];
    const int z = blockIdx.z;
    const int tx = threadIdx.x & 31, ty0 = threadIdx.x >> 5;   // 32 x 8
    if (z < 64) {
        const float* s = ctx + (size_t)z * 65536;
        const int c0 = blockIdx.x * 32, r0 = blockIdx.y * 32;
#pragma unroll
        for (int i = 0; i < 4; i++) {
            int ty = ty0 + i * 8;
            float v = s[(size_t)(r0 + ty) * 256 + c0 + tx];
            tile[ty][tx] = v;
            CtP[(size_t)z * 65536 + (size_t)(r0 + ty) * 256 + c0 + tx] = f2h(v);
        }
        __syncthreads();
#pragma unroll
        for (int i = 0; i < 4; i++) {
            int ty = ty0 + i * 8;
            CtH[(size_t)z * 65536 + (size_t)(c0 + ty) * 256 + r0 + tx] = f2h(tile[tx][ty]);
        }
    } else {
        const int r0 = (z - 64) * 256 + blockIdx.y * 32;       // W rows
        const int c0 = blockIdx.x * 32;
#pragma unroll
        for (int i = 0; i < 4; i++) {
            int ty = ty0 + i * 8;
            float v = Wsrc[(size_t)(r0 + ty) * 256 + c0 + tx];
            tile[ty][tx] = v;
            Wp[(size_t)(r0 + ty) * 256 + c0 + tx] = f2h(v);
        }
        __syncthreads();
#pragma unroll
        for (int i = 0; i < 4; i++) {
            int ty = ty0 + i * 8;
            WtH[(size_t)(c0 + ty) * 1024 + r0 + tx] = f2h(tile[tx][ty]);
        }
    }
}

// ---------------------------------------------------------------------------
// Mega kernel. 256 blocks x 512 thr (8 waves). Block = (b, m0) 32-row band.
// smB[2]: 40 DMA chunks [256 rows][64 k] fp16, XOR-swizzled (16B grp ^ row&7)
//   achieved by pre-swizzling the per-lane GLOBAL address (linear LDS dest).
// smA: M -> P -> Yt (32x256 fp16, col-group swizzle ^ row&7).
// smC[2]: wc 32x64 fp16 (M phase A), reg-staged with on-the-fly convert.
__global__ __launch_bounds__(512, 2) void k_mega(
    const float* __restrict__ wc, const u16* __restrict__ WtH,
    const u16* __restrict__ CtH, const u16* __restrict__ CtP,
    const u16* __restrict__ Wp,
    float* __restrict__ out1, float* __restrict__ out2)
{
    __shared__ __align__(16) u16 smA[32 * 256];      // 16 KB
    __shared__ __align__(16) u16 smB[2][256 * 64];   // 64 KB
    __shared__ __align__(16) u16 smC[2][32 * 64];    // 8 KB
    __shared__ float red[32][8];

    const int sbl = xcd_swz((int)blockIdx.x, (int)gridDim.x);
    const int b  = sbl >> 2;
    const int m0 = (sbl & 3) * 32;
    const int t = threadIdx.x;
    const int w = t >> 6, g = (t >> 4) & 3, r = t & 15;

    const u16* CtHb = CtH + (size_t)b * 65536;
    const u16* CtPb = CtP + (size_t)b * 65536;
    const int gi0 = b * 128 + m0;

    // ---- chunk DMA: chunk c -> smB[bi]; per wave 4 x gload16 (8 rows each)
    auto ISSUE = [&](int c, int bi) {
        const u16* base; int stride;
        if (c < 16)      { base = WtH + c * 64;                 stride = 1024; }
        else if (c < 20) { base = CtHb + (c - 16) * 64;         stride = 256;  }
        else if (c < 24) { base = CtPb + (c - 20) * 64;         stride = 256;  }
        else             { base = Wp + (size_t)((c - 24) >> 2) * 65536
                                  + ((c - 24) & 3) * 64;        stride = 256;  }
        const int lr0 = w * 32;
#pragma unroll
        for (int i = 0; i < 4; i++) {
            const int row = lr0 + i * 8 + ((t & 63) >> 3);
            const u16* gp = base + (size_t)row * stride + (((t & 7) ^ (row & 7)) << 3);
            gload16(gp, &smB[bi][(lr0 + i * 8) * 64]);
        }
    };

    // ---- M-phase A staging: wc rows gi0..gi0+31, k-slice 64 f32 -> fp16
    float4 fa;
    auto LOADA = [&](int c) {
        fa = *((const float4*)(wc + (size_t)(gi0 + (t >> 4)) * 1024 + c * 64) + (t & 15));
    };
    auto STOREA = [&](int bi) {
        const int row = t >> 4, grp = (t & 15) >> 1, half = t & 1;
        uint2 d = make_uint2(pk2h(fa.x, fa.y), pk2h(fa.z, fa.w));
        *(uint2*)&smC[bi][row * 64 + ((grp ^ (row & 7)) << 3) + (half << 2)] = d;
    };

    // ================= phase M: chunks 0-15 (B = WtH) =================
    f32x4 accM[2][2] = {};
    LOADA(0); STOREA(0); LOADA(1);
    ISSUE(0, 0);
    __syncthreads();

#pragma unroll 1
    for (int c = 0; c < 16; ++c) {
        ISSUE(c + 1, (c + 1) & 1);                 // c=15 -> chunk 16 (CtH0)
#pragma unroll
        for (int kh = 0; kh < 2; kh++) {
            f16x8 aF[2], bF[2];
#pragma unroll
            for (int mi = 0; mi < 2; mi++)
                aF[mi] = *(const f16x8*)&smC[c & 1]
                    [(mi * 16 + r) * 64 + ((((kh << 2) | g) ^ (r & 7)) << 3)];
#pragma unroll
            for (int ni = 0; ni < 2; ni++) {
                const int row = w * 32 + ni * 16 + r;
                bF[ni] = *(const f16x8*)&smB[c & 1]
                    [row * 64 + ((((kh << 2) | g) ^ (row & 7)) << 3)];
            }
#pragma unroll
            for (int mi = 0; mi < 2; mi++)
#pragma unroll
                for (int ni = 0; ni < 2; ni++)
                    accM[mi][ni] = MFMA_F16(aF[mi], bF[ni], accM[mi][ni]);
        }
        if (c + 1 < 16) { STOREA((c + 1) & 1); if (c + 2 < 16) LOADA(c + 2); }
        __syncthreads();
    }

    // park M (fp16) into smA
#pragma unroll
    for (int mi = 0; mi < 2; mi++)
#pragma unroll
        for (int ni = 0; ni < 2; ni++)
#pragma unroll
            for (int rr = 0; rr < 4; rr++) {
                const int lrow = mi * 16 + 4 * g + rr;
                const int col  = w * 32 + ni * 16 + r;
                smA[lrow * 256 + (((col >> 3) ^ (lrow & 7)) << 3) + (col & 7)]
                    = f2h(accM[mi][ni][rr]);
            }
    __syncthreads();

    // ================= phase logits: chunks 16-19 (B = CtH) =================
    f32x4 accL[2][2] = {};
#pragma unroll 1
    for (int lc = 0; lc < 4; ++lc) {
        ISSUE(17 + lc, (17 + lc) & 1);             // lc=3 -> chunk 20 (CtP0)
#pragma unroll
        for (int kh = 0; kh < 2; kh++) {
            const int grp = lc * 8 + kh * 4 + g;
            f16x8 aF[2], bF[2];
#pragma unroll
            for (int mi = 0; mi < 2; mi++)
                aF[mi] = *(const f16x8*)&smA
                    [(mi * 16 + r) * 256 + ((grp ^ (r & 7)) << 3)];
#pragma unroll
            for (int ni = 0; ni < 2; ni++) {
                const int row = w * 32 + ni * 16 + r;
                bF[ni] = *(const f16x8*)&smB[lc & 1]
                    [row * 64 + ((((kh << 2) | g) ^ (row & 7)) << 3)];
            }
#pragma unroll
            for (int mi = 0; mi < 2; mi++)
#pragma unroll
                for (int ni = 0; ni < 2; ni++)
                    accL[mi][ni] = MFMA_F16(aF[mi], bF[ni], accL[mi][ni]);
        }
        __syncthreads();
    }

    // ================= softmax over 256 cols =================
    float s_[2][4];
#pragma unroll
    for (int mi = 0; mi < 2; mi++)
#pragma unroll
        for (int rr = 0; rr < 4; rr++) {
            float mx = fmaxf(accL[mi][0][rr], accL[mi][1][rr]);
#pragma unroll
            for (int m = 1; m < 16; m <<= 1) mx = fmaxf(mx, __shfl_xor(mx, m));
            if (r == 0) red[mi * 16 + 4 * g + rr][w] = mx;
        }
    __syncthreads();
#pragma unroll
    for (int mi = 0; mi < 2; mi++)
#pragma unroll
        for (int rr = 0; rr < 4; rr++) {
            const int lrow = mi * 16 + 4 * g + rr;
            float gmx = red[lrow][0];
#pragma unroll
            for (int j = 1; j < 8; j++) gmx = fmaxf(gmx, red[lrow][j]);
            float s = 0.f;
#pragma unroll
            for (int ni = 0; ni < 2; ni++) {
                float e = __expf(accL[mi][ni][rr] - gmx);
                accL[mi][ni][rr] = e;
                s += e;
            }
#pragma unroll
            for (int m = 1; m < 16; m <<= 1) s += __shfl_xor(s, m);
            s_[mi][rr] = s;
        }
    __syncthreads();
#pragma unroll
    for (int mi = 0; mi < 2; mi++)
#pragma unroll
        for (int rr = 0; rr < 4; rr++)
            if (r == 0) red[mi * 16 + 4 * g + rr][w] = s_[mi][rr];
    __syncthreads();
    // normalize + park P into smA (M dead)
#pragma unroll
    for (int mi = 0; mi < 2; mi++)
#pragma unroll
        for (int rr = 0; rr < 4; rr++) {
            const int lrow = mi * 16 + 4 * g + rr;
            float sum = red[lrow][0];
#pragma unroll
            for (int j = 1; j < 8; j++) sum += red[lrow][j];
            const float inv = 1.f / sum;
#pragma unroll
            for (int ni = 0; ni < 2; ni++) {
                const float v = accL[mi][ni][rr] * inv;
                const int col = w * 32 + ni * 16 + r;
                smA[lrow * 256 + (((col >> 3) ^ (lrow & 7)) << 3) + (col & 7)] = f2h(v);
            }
        }
    __syncthreads();

    // ---- out2 = P^T: thread t<256 owns column l, writes 128 B contiguous f32
    if (t < 256) {
        const int l = t;
        float vals[32];
#pragma unroll
        for (int row = 0; row < 32; row++)
            vals[row] = h2f(smA[row * 256 + (((l >> 3) ^ (row & 7)) << 3) + (l & 7)]);
        float4* dst = (float4*)(out2 + (size_t)b * 32768 + (size_t)l * 128 + m0);
#pragma unroll
        for (int q = 0; q < 8; q++)
            dst[q] = make_float4(vals[4 * q], vals[4 * q + 1],
                                 vals[4 * q + 2], vals[4 * q + 3]);
    }

    // ================= phase PV: chunks 20-23 (B = CtP) =================
    f32x4 accP[2][2] = {};
#pragma unroll 1
    for (int pc = 0; pc < 4; ++pc) {
        ISSUE(21 + pc, (21 + pc) & 1);             // pc=3 -> chunk 24 (Wp0)
#pragma unroll
        for (int kh = 0; kh < 2; kh++) {
            const int grp = pc * 8 + kh * 4 + g;
            f16x8 aF[2], bF[2];
#pragma unroll
            for (int mi = 0; mi < 2; mi++)
                aF[mi] = *(const f16x8*)&smA
                    [(mi * 16 + r) * 256 + ((grp ^ (r & 7)) << 3)];
#pragma unroll
            for (int ni = 0; ni < 2; ni++) {
                const int row = w * 32 + ni * 16 + r;
                bF[ni] = *(const f16x8*)&smB[pc & 1]
                    [row * 64 + ((((kh << 2) | g) ^ (row & 7)) << 3)];
            }
#pragma unroll
            for (int mi = 0; mi < 2; mi++)
#pragma unroll
                for (int ni = 0; ni < 2; ni++)
                    accP[mi][ni] = MFMA_F16(aF[mi], bF[ni], accP[mi][ni]);
        }
        __syncthreads();
    }

    // park Yt into smA (P dead)
#pragma unroll
    for (int mi = 0; mi < 2; mi++)
#pragma unroll
        for (int ni = 0; ni < 2; ni++)
#pragma unroll
            for (int rr = 0; rr < 4; rr++) {
                const int lrow = mi * 16 + 4 * g + rr;
                const int col  = w * 32 + ni * 16 + r;
                smA[lrow * 256 + (((col >> 3) ^ (lrow & 7)) << 3) + (col & 7)]
                    = f2h(accP[mi][ni][rr]);
            }
    __syncthreads();

    // ================= phase out1: chunks 24-39 (B = Wp) =================
    f16x8 aY[2][8];                                 // Yt fragments, all K=256
#pragma unroll
    for (int mi = 0; mi < 2; mi++)
#pragma unroll
        for (int kq = 0; kq < 8; kq++)
            aY[mi][kq] = *(const f16x8*)&smA
                [(mi * 16 + r) * 256 + (((kq * 4 + g) ^ (r & 7)) << 3)];

#pragma unroll 1
    for (int ns = 0; ns < 4; ++ns) {
        f32x4 acc3[2][2] = {};
#pragma unroll
        for (int kc = 0; kc < 4; ++kc) {
            const int j = ns * 4 + kc;
            if (j < 15) ISSUE(25 + j, (25 + j) & 1);
#pragma unroll
            for (int kh = 0; kh < 2; kh++) {
                const int kq = kc * 2 + kh;        // static
                f16x8 bF[2];
#pragma unroll
                for (int ni = 0; ni < 2; ni++) {
                    const int row = w * 32 + ni * 16 + r;
                    bF[ni] = *(const f16x8*)&smB[kc & 1]
                        [row * 64 + ((((kh << 2) | g) ^ (row & 7)) << 3)];
                }
#pragma unroll
                for (int mi = 0; mi < 2; mi++)
#pragma unroll
                    for (int ni = 0; ni < 2; ni++)
                        acc3[mi][ni] = MFMA_F16(aY[mi][kq], bF[ni], acc3[mi][ni]);
            }
            __syncthreads();
        }
        // write out1 n-super-chunk ns (f32, coalesced 64 B / 16 lanes)
#pragma unroll
        for (int mi = 0; mi < 2; mi++)
#pragma unroll
            for (int ni = 0; ni < 2; ni++) {
                const int col = ns * 256 + w * 32 + ni * 16 + r;
#pragma unroll
                for (int rr = 0; rr < 4; rr++)
                    out1[(size_t)(gi0 + mi * 16 + 4 * g + rr) * 1024 + col]
                        = acc3[mi][ni][rr];
            }
    }
}

// ---------------------------------------------------------------------------
extern "C" void kernel_launch(void* const* d_in, const int* in_sizes, int n_in,
                              void* d_out, int out_size, void* d_ws, size_t ws_size,
                              hipStream_t stream) {
    const int B = 64, IDF = 128, CDF = 256, L = 256, S2 = 1024;
    const float* wc  = (const float*)d_in[0];   // [B, IDF, S2] = [8192][1024]
    const float* ctx = (const float*)d_in[1];   // [B, CDF, L]
    const float* W   = (const float*)d_in[2];   // [S2, CDF]
    float* out1 = (float*)d_out;                          // [B,IDF,S2]
    float* out2 = (float*)d_out + (size_t)B * IDF * S2;   // [B,L,IDF]

    char* ws = (char*)d_ws;
    size_t off = 0;
    auto alloc = [&](size_t bytes) -> char* {
        char* p = ws + off;
        off += (bytes + 255) & ~(size_t)255;
        return p;
    };
    u16* WtH = (u16*)alloc((size_t)CDF * S2 * 2);        // W^T fp16 [256][1024]
    u16* Wp  = (u16*)alloc((size_t)S2 * CDF * 2);        // W   fp16 [1024][256]
    u16* CtH = (u16*)alloc((size_t)B * L * CDF * 2);     // ctx^T fp16 [B][l][c]
    u16* CtP = (u16*)alloc((size_t)B * CDF * L * 2);     // ctx fp16  [B][c][l]
    (void)ws_size; // ~18 MB

    // converts: ctx -> CtH + CtP ; W -> WtH + Wp
    k_tcvt_all<<<dim3(8, 8, 68), 256, 0, stream>>>(W, ctx, WtH, Wp, CtH, CtP);

    // mega: M + logits + softmax + out2 + PV + out1, 256 blocks x 512 thr
    k_mega<<<256, 512, 0, stream>>>(wc, WtH, CtH, CtP, Wp, out1, out2);
}